// Round 11
// baseline (498.552 us; speedup 1.0000x reference)
//
#include <hip/hip_runtime.h>
#include <hip/hip_bf16.h>
#include <stdint.h>

// ---------------------------------------------------------------------------
// UNetAttention: hs(2,4096,1280) fp32; self-attention H=8, D=160; out fp32.
// GEMMs via mfma_f32_16x16x32_bf16; flash attention via mfma_f32_32x32x16_bf16
// with swapped QK^T, fully in-register P, and KV-SPLIT: 8-wave blocks =
// 2 kv-half groups x 4 q-waves.  KVBLK=32 so LDS = 36864 B/block -> 2 blocks
// co-resident per CU -> 4 waves/SIMD (round 10's 81920 B hit the 160KB pool
// exactly and co-residency failed -> stuck at 2 waves/SIMD).
// ---------------------------------------------------------------------------

using bf16x8 = __attribute__((ext_vector_type(8))) short;  // 8 bf16 in 4 VGPRs
using f32x4  = __attribute__((ext_vector_type(4))) float;  // 16x16 MFMA C/D
using f32x16 = __attribute__((ext_vector_type(16))) float; // 32x32 MFMA C/D

__device__ __forceinline__ short f2bf(float f) {
    union { float f; uint32_t u; } v; v.f = f;
    uint32_t r = v.u + 0x7fffu + ((v.u >> 16) & 1u);   // RNE
    return (short)(r >> 16);
}

// async global->LDS DMA, 16B per lane.  LDS dest = wave-uniform base + lane*16.
__device__ __forceinline__ void async16(const short* g, short* l) {
    __builtin_amdgcn_global_load_lds(
        (const __attribute__((address_space(1))) void*)g,
        (__attribute__((address_space(3))) void*)l, 16, 0, 0);
}

// ---------------------------------------------------------------------------
// hs fp32 -> bf16 (row-major, for DMA-staged QKV GEMM A)
// ---------------------------------------------------------------------------
__global__ __launch_bounds__(256) void cast_hs(
    const float* __restrict__ hs, short* __restrict__ out)
{
    int i = (blockIdx.x * 256 + threadIdx.x) * 4;
    float4 v = *(const float4*)&hs[i];
    short4 s; s.x = f2bf(v.x); s.y = f2bf(v.y); s.z = f2bf(v.z); s.w = f2bf(v.w);
    *(short4*)&out[i] = s;
}

// ---------------------------------------------------------------------------
// Weight transpose+cast: w[k][n] fp32 -> wT[n][k] bf16.
// ---------------------------------------------------------------------------
__global__ __launch_bounds__(256) void transpose_w(
    const float* __restrict__ w0, const float* __restrict__ w1,
    const float* __restrict__ w2, const float* __restrict__ w3,
    short* __restrict__ wqkvT, short* __restrict__ woutT)
{
    __shared__ float tile[32][33];
    int z = blockIdx.z;
    const float* src = (z == 0) ? w0 : (z == 1) ? w1 : (z == 2) ? w2 : w3;
    short* dst = (z == 3) ? woutT : (wqkvT + (long)z * 1280 * 1280);
    int k0 = blockIdx.x * 32, n0 = blockIdx.y * 32;
    int t = threadIdx.x, r = t >> 5, c = t & 31;
#pragma unroll
    for (int i = 0; i < 4; i++)
        tile[r + i * 8][c] = src[(long)(k0 + r + i * 8) * 1280 + n0 + c];
    __syncthreads();
#pragma unroll
    for (int i = 0; i < 4; i++)
        dst[(long)(n0 + r + i * 8) * 1280 + k0 + c] = f2bf(tile[c][r + i * 8]);
}

// ---------------------------------------------------------------------------
// v_h [bh][4096][160] bf16 -> v_t [bh][160][4096] bf16
// ---------------------------------------------------------------------------
__global__ __launch_bounds__(256) void transpose_v(
    const short* __restrict__ v, short* __restrict__ vt)
{
    __shared__ short tile[32][33];
    int s0 = blockIdx.x * 32, d0 = blockIdx.y * 32;
    long bh = blockIdx.z;
    const short* src = v + bh * 4096 * 160;
    short* dst = vt + bh * 160 * 4096;
    int t = threadIdx.x, r = t >> 5, c = t & 31;
#pragma unroll
    for (int i = 0; i < 4; i++)
        tile[r + i * 8][c] = src[(s0 + r + i * 8) * 160 + d0 + c];
    __syncthreads();
#pragma unroll
    for (int i = 0; i < 4; i++)
        dst[(d0 + r + i * 8) * 4096 + s0 + c] = tile[c][r + i * 8];
}

// ---------------------------------------------------------------------------
// 128x128 MFMA GEMM, BK=64, global_load_lds staging, XOR-swizzled LDS.
// MODE 0: QKV epilogue (scatter to q_h/k_h/v_h; q pre-scaled by scale*log2e).
// MODE 1: out-proj epilogue (fp32 + bias).
// ---------------------------------------------------------------------------
template <int MODE>
__global__ __launch_bounds__(256, 3) void gemm_k(
    const short* __restrict__ A, const short* __restrict__ BT,
    short* __restrict__ q_h, short* __restrict__ k_h, short* __restrict__ v_h,
    float* __restrict__ outp, const float* __restrict__ bias)
{
    __shared__ __align__(16) short A_lds[128 * 64];
    __shared__ __align__(16) short B_lds[128 * 64];

    int t = threadIdx.x, wave = t >> 6, lane = t & 63;
    int quad = lane >> 4, l15 = lane & 15, h7 = l15 & 7;
    int wr = wave >> 1, wc = wave & 1;
    int m0 = blockIdx.y * 128, n0 = blockIdx.x * 128;

    f32x4 acc[4][4] = {};

    for (int kt = 0; kt < 1280; kt += 64) {
        __syncthreads();
#pragma unroll
        for (int i = 0; i < 4; i++) {
            int chunk = wave * 4 + i;
            int c = chunk * 64 + lane;
            int row = c >> 3, j = (c & 7) ^ (row & 7);
            async16(A  + (long)(m0 + row) * 1280 + kt + j * 8, A_lds + chunk * 512);
            async16(BT + (long)(n0 + row) * 1280 + kt + j * 8, B_lds + chunk * 512);
        }
        __syncthreads();

#pragma unroll
        for (int dk = 0; dk < 2; dk++) {
            bf16x8 a[4], b[4];
#pragma unroll
            for (int mi = 0; mi < 4; mi++) {
                int row = wr * 64 + mi * 16 + l15;
                a[mi] = *(const bf16x8*)&A_lds[row * 64 + ((dk * 4 + quad) ^ h7) * 8];
            }
#pragma unroll
            for (int ni = 0; ni < 4; ni++) {
                int row = wc * 64 + ni * 16 + l15;
                b[ni] = *(const bf16x8*)&B_lds[row * 64 + ((dk * 4 + quad) ^ h7) * 8];
            }
#pragma unroll
            for (int mi = 0; mi < 4; mi++)
#pragma unroll
                for (int ni = 0; ni < 4; ni++)
                    acc[mi][ni] = __builtin_amdgcn_mfma_f32_16x16x32_bf16(
                        a[mi], b[ni], acc[mi][ni], 0, 0, 0);
        }
    }

    const float SL2E = 0.07905694150420949f * 1.4426950408889634f;
#pragma unroll
    for (int mi = 0; mi < 4; mi++) {
#pragma unroll
        for (int ni = 0; ni < 4; ni++) {
#pragma unroll
            for (int r = 0; r < 4; r++) {
                int gr = m0 + wr * 64 + mi * 16 + quad * 4 + r;
                int gc = n0 + wc * 64 + ni * 16 + l15;
                float val = acc[mi][ni][r];
                if (MODE == 0) {
                    int which = gc / 1280;
                    int c1 = gc - which * 1280;
                    int hh = c1 / 160, d = c1 - hh * 160;
                    int b_ = gr >> 12, s = gr & 4095;
                    long addr = (((long)(b_ * 8 + hh)) * 4096 + s) * 160 + d;
                    if (which == 0) val *= SL2E;   // fold scale*log2e into Q
                    short* dst = (which == 0) ? q_h : (which == 1) ? k_h : v_h;
                    dst[addr] = f2bf(val);
                } else {
                    outp[(long)gr * 1280 + gc] = val + bias[gc];
                }
            }
        }
    }
}

// ---------------------------------------------------------------------------
// Flash attention, 32x32x16 MFMA, swapped QK^T, in-register P, KV-SPLIT,
// KVBLK=32.
//
// Block = 512 threads = 8 waves = 2 kv-half groups (kvh = wave>>2) x 4 q-waves
// (qw = wave&3).  Group kvh processes k in [kvh*2048, (kvh+1)*2048), 32 k per
// iteration (64 iters).  LDS per group = Kb128 (32x128 bf16, 8KB) + Vb
// (160x32 bf16, 10KB) = 18KB; block total 36864 B -> 2 blocks/CU co-resident
// -> 16 waves/CU = 4 waves/SIMD (the round-10 kv-split goal; 81920 B failed
// exact-fit co-residency).
//
// K d=128..159 ("tail") is NOT staged: per-lane 16B register loads from
// global (L2/L3-hot; same bytes the LDS path would deliver — layout
// identical, so QK math is unchanged).  Tail(t+1) loads issue next to
// stageK(t+1) after barrier B and are drained by the vmcnt(0) before
// barrier E -> full latency cover, consumed in QK(t+1).
//
// V staging = 10 chunks of 1KB: waves 0,1 issue 3, waves 2,3 issue 2
// (vmcnt(0) drains are per-wave, so non-uniform counts are safe; prologue
// uses vmcnt(2), correct for both counts).  V swizzle s(row) =
// (row&3)^((row>>2)&3): 2-bit slot XOR, conflict-free per 8-lane phase.
//
// Per-wave math otherwise identical to round 7/10 (verified): swapped QK^T
// (single chain), p = exp2(s-16), cvt_pk + permlane32_swap A-frag assembly,
// raw-e row-sum, plain-addition kv-half combine.
//
// Epilogue: lsum exchange, then o[] exchange in 3 chunks of <=8 planes
// (8192 floats <= 9216-float LDS cap), all indices compile-time.
// ---------------------------------------------------------------------------
__global__ __launch_bounds__(512, 2) void flash_k(
    const short* __restrict__ q_h, const short* __restrict__ k_h,
    const short* __restrict__ v_t, short* __restrict__ attn_out)
{
    __shared__ __align__(16) short LDS[2 * 9216];   // 36864 B flat
    // per-group set (9216 shorts): Kb128 (4096) | Vb (5120)

    int t = threadIdx.x, wave = t >> 6, lane = t & 63;
    int l31 = lane & 31, hi = lane >> 5;
    int qw = wave & 3, kvh = wave >> 2;
    int qt = blockIdx.x;
    long bh = blockIdx.y;
    int b = (int)(bh >> 3), h = (int)(bh & 7);

    short* Kb128 = LDS + kvh * 9216;
    short* Vb    = Kb128 + 4096;
    long kbase = bh * 4096 + kvh * 2048;    // this group's k origin (rows of K)

    // Q B-frags: lane holds Q[q = qt*128 + qw*32 + l31][d = dk*16 + hi*8 + 0..7]
    bf16x8 qf[10];
    {
        const short* qg = q_h + (bh * 4096 + qt * 128 + qw * 32 + l31) * 160;
#pragma unroll
        for (int dk = 0; dk < 10; dk++)
            qf[dk] = *(const bf16x8*)&qg[dk * 16 + hi * 8];
    }

    // K main (d 0..127) staging: 8 chunks of 1KB -> 2 issues/wave
    auto stageK = [&](int k0) {
        const short* kg = k_h + (kbase + k0) * 160;
#pragma unroll
        for (int i = 0; i < 2; i++) {
            int chunk = qw * 2 + i;
            int c = chunk * 64 + lane;
            int row = c >> 4, j = (c & 15) ^ (row & 7);
            async16(kg + row * 160 + j * 8, Kb128 + chunk * 512);
        }
    };
    // V staging: 10 chunks of 1KB -> waves 0,1: 3 issues; waves 2,3: 2
    auto stageVc = [&](int chunk, int k0) {
        int c = chunk * 64 + lane;
        int row = c >> 2;
        int sw = (row & 3) ^ ((row >> 2) & 3);
        int j = (c & 3) ^ sw;
        async16(v_t + (bh * 160 + row) * 4096 + kvh * 2048 + k0 + j * 8,
                Vb + chunk * 512);
    };
    auto stageV = [&](int k0) {
        stageVc(qw * 2 + 0, k0);
        stageVc(qw * 2 + 1, k0);
        if (qw < 2) stageVc(8 + qw, k0);
    };
    // K tail (d 128..159) -> registers (per-lane 16B loads, layout == A-frag)
    bf16x8 kt8, kt9;
    auto loadTail = [&](int k0) {
        const short* kgt = k_h + (kbase + k0 + l31) * 160;
        kt8 = *(const bf16x8*)&kgt[128 + hi * 8];
        kt9 = *(const bf16x8*)&kgt[144 + hi * 8];
    };

    f32x16 o[5] = {};    // O accumulators: o[ct][reg], d = ct*32+l31
    float lacc = 0.f;    // row-sum partial (own 32-k slice per tile)

    // prologue: K(0)+V(0)+tail(0) in flight; wait K(0)+V(0) (own oldest),
    // leaving only tails outstanding (compiler waits those at first use).
    stageK(0);
    stageV(0);
    loadTail(0);
    asm volatile("s_waitcnt vmcnt(2)" ::: "memory");
    __builtin_amdgcn_s_barrier();

    for (int k0 = 0; k0 < 2048; k0 += 32) {
        // ---- QK^T (swapped) ----
        f32x16 s = {};
        __builtin_amdgcn_s_setprio(1);
#pragma unroll
        for (int dk = 0; dk < 8; dk++) {
            bf16x8 ka = *(const bf16x8*)
                &Kb128[l31 * 128 + (((dk * 2 + hi) ^ (l31 & 7)) * 8)];
            s = __builtin_amdgcn_mfma_f32_32x32x16_bf16(ka, qf[dk], s, 0, 0, 0);
        }
        s = __builtin_amdgcn_mfma_f32_32x32x16_bf16(kt8, qf[8], s, 0, 0, 0);
        s = __builtin_amdgcn_mfma_f32_32x32x16_bf16(kt9, qf[9], s, 0, 0, 0);
        __builtin_amdgcn_s_setprio(0);

        // ---- softmax: p = exp2(s-16); reg -> k = (reg&3)+8*(reg>>2)+4*hi ----
        uint32_t u[4][2];
#pragma unroll
        for (int rg = 0; rg < 4; rg++) {
            float e0 = exp2f(s[rg * 4 + 0] - 16.f);
            float e1 = exp2f(s[rg * 4 + 1] - 16.f);
            float e2 = exp2f(s[rg * 4 + 2] - 16.f);
            float e3 = exp2f(s[rg * 4 + 3] - 16.f);
            uint32_t pk0, pk1;
            asm("v_cvt_pk_bf16_f32 %0, %1, %2" : "=v"(pk0) : "v"(e0), "v"(e1));
            asm("v_cvt_pk_bf16_f32 %0, %1, %2" : "=v"(pk1) : "v"(e2), "v"(e3));
            u[rg][0] = pk0; u[rg][1] = pk1;
            lacc += (e0 + e1) + (e2 + e3);   // raw-e row-sum (tree)
        }
        uint32_t pw[2][4];   // A-frag words, pw[g][w]: k = 16g+8hi+2w+{0,1}
#pragma unroll
        for (int ksl = 0; ksl < 2; ksl++)
#pragma unroll
            for (int c = 0; c < 2; c++) {
                auto r = __builtin_amdgcn_permlane32_swap(
                    u[2 * ksl][c], u[2 * ksl + 1][c], false, false);
                pw[ksl][c]     = (uint32_t)r[0];
                pw[ksl][c + 2] = (uint32_t)r[1];
            }

        // V(t) landed (only V(t) outstanding); all waves done reading K(t)
        asm volatile("s_waitcnt vmcnt(0)" ::: "memory");
        asm volatile("s_waitcnt lgkmcnt(0)" ::: "memory");
        __builtin_amdgcn_s_barrier();                      // B

        if (k0 + 32 < 2048) {
            stageK(k0 + 32);      // lands under PV(t)
            loadTail(k0 + 32);    // drained at E, used in QK(t+1)
        }

        // ---- O += P V ----
        __builtin_amdgcn_s_setprio(1);
#pragma unroll
        for (int ks = 0; ks < 2; ks++) {
            union { uint32_t w[4]; bf16x8 v; } ap;
            ap.w[0] = pw[ks][0]; ap.w[1] = pw[ks][1];
            ap.w[2] = pw[ks][2]; ap.w[3] = pw[ks][3];
#pragma unroll
            for (int ct = 0; ct < 5; ct++) {
                int row = ct * 32 + l31;
                int sw = (row & 3) ^ ((row >> 2) & 3);
                bf16x8 bv = *(const bf16x8*)
                    &Vb[row * 32 + (((ks * 2 + hi) ^ sw) * 8)];
                o[ct] = __builtin_amdgcn_mfma_f32_32x32x16_bf16(ap.v, bv, o[ct], 0, 0, 0);
            }
        }
        __builtin_amdgcn_s_setprio(0);

        // K(t+1)+tail(t+1) landed; all waves done with V(t)
        asm volatile("s_waitcnt vmcnt(0)" ::: "memory");
        asm volatile("s_waitcnt lgkmcnt(0)" ::: "memory");
        __builtin_amdgcn_s_barrier();                      // E

        if (k0 + 32 < 2048) stageV(k0 + 32);   // lands under QK(t+1)+SM(t+1)
    }

    // ---- epilogue: combine kv-halves via LDS, normalize, write ----
    float lsum = lacc + __shfl_xor(lacc, 32);

    // phase 1: lsum exchange (128 floats at LDS base)
    float* exL = (float*)LDS;
    if (kvh == 1 && hi == 0) exL[qw * 32 + l31] = lsum;
    asm volatile("s_waitcnt lgkmcnt(0)" ::: "memory");
    __builtin_amdgcn_s_barrier();
    float lsum_o = 0.f;
    if (kvh == 0) lsum_o = exL[qw * 32 + l31];
    asm volatile("s_waitcnt lgkmcnt(0)" ::: "memory");
    __builtin_amdgcn_s_barrier();    // reads drained before region reuse

    // phase 2: o[] exchange, 3 chunks of <=8 planes (fits 9216-float LDS)
    float* exO = (float*)LDS;
#define XCHUNK(P0, P1)                                                         \
    if (kvh == 1) {                                                            \
        _Pragma("unroll")                                                      \
        for (int p = P0; p < P1; p++) {                                        \
            float4 v4 = { o[p >> 2][(p & 3) * 4 + 0], o[p >> 2][(p & 3) * 4 + 1], \
                          o[p >> 2][(p & 3) * 4 + 2], o[p >> 2][(p & 3) * 4 + 3] }; \
            *(float4*)&exO[(p - P0) * 1024 + qw * 256 + lane * 4] = v4;        \
        }                                                                      \
    }                                                                          \
    asm volatile("s_waitcnt lgkmcnt(0)" ::: "memory");                         \
    __builtin_amdgcn_s_barrier();                                              \
    if (kvh == 0) {                                                            \
        _Pragma("unroll")                                                      \
        for (int p = P0; p < P1; p++) {                                        \
            float4 v4 = *(const float4*)&exO[(p - P0) * 1024 + qw * 256 + lane * 4]; \
            o[p >> 2][(p & 3) * 4 + 0] += v4.x; o[p >> 2][(p & 3) * 4 + 1] += v4.y; \
            o[p >> 2][(p & 3) * 4 + 2] += v4.z; o[p >> 2][(p & 3) * 4 + 3] += v4.w; \
        }                                                                      \
    }                                                                          \
    asm volatile("s_waitcnt lgkmcnt(0)" ::: "memory");                         \
    __builtin_amdgcn_s_barrier();

    XCHUNK(0, 8)
    XCHUNK(8, 16)
    XCHUNK(16, 20)
#undef XCHUNK

    if (kvh == 0) {
        float inv = 1.0f / (lsum + lsum_o);   // valid for q = l31 on every lane
        float iv[16];
#pragma unroll
        for (int r = 0; r < 16; r++)
            iv[r] = __shfl(inv, (r & 3) + 8 * (r >> 2) + 4 * hi);

#pragma unroll
        for (int ct = 0; ct < 5; ct++)
#pragma unroll
            for (int r = 0; r < 16; r++) {
                int crow = (r & 3) + 8 * (r >> 2) + 4 * hi;
                int gr = b * 4096 + qt * 128 + qw * 32 + crow;
                int gc = h * 160 + ct * 32 + l31;
                attn_out[(long)gr * 1280 + gc] = f2bf(o[ct][r] * iv[r]);
            }
    }
}

// ---------------------------------------------------------------------------
// Launch
// ---------------------------------------------------------------------------
extern "C" void kernel_launch(void* const* d_in, const int* in_sizes, int n_in,
                              void* d_out, int out_size, void* d_ws, size_t ws_size,
                              hipStream_t stream)
{
    const float* hs = (const float*)d_in[0];
    const float* wq = (const float*)d_in[1];
    const float* wk = (const float*)d_in[2];
    const float* wv = (const float*)d_in[3];
    const float* wo = (const float*)d_in[4];
    const float* bo = (const float*)d_in[5];
    float* out = (float*)d_out;

    // workspace layout (bytes), ~97 MB total
    char* ws = (char*)d_ws;
    short* wqkvT = (short*)(ws + 0);            // 3840*1280*2 = 9,830,400
    short* woutT = (short*)(ws + 9830400);      // 1280*1280*2 = 3,276,800
    short* q_h   = (short*)(ws + 13107200);     // 16*4096*160*2 = 20,971,520
    short* k_h   = (short*)(ws + 34078720);
    short* v_t   = (short*)(ws + 55050240);     // also hs_bf before transpose_v
    short* v_h   = (short*)(ws + 76021760);     // aliased with attn (disjoint lifetimes)
    short* attn  = v_h;
    short* hs_bf = v_t;   // hs_bf dead before v_t is born

    cast_hs<<<10240, 256, 0, stream>>>(hs, hs_bf);
    transpose_w<<<dim3(40, 40, 4), 256, 0, stream>>>(wq, wk, wv, wo, wqkvT, woutT);
    gemm_k<0><<<dim3(30, 64), 256, 0, stream>>>(hs_bf, wqkvT, q_h, k_h, v_h,
                                                nullptr, nullptr);
    transpose_v<<<dim3(128, 5, 16), 256, 0, stream>>>(v_h, v_t);
    flash_k<<<dim3(32, 16), 512, 0, stream>>>(q_h, k_h, v_t, attn);
    gemm_k<1><<<dim3(10, 64), 256, 0, stream>>>(attn, woutT, nullptr, nullptr,
                                                nullptr, out, bo);
}